// Round 1
// baseline (402.164 us; speedup 1.0000x reference)
//
#include <hip/hip_runtime.h>

#define CH    1024
#define NST   16
#define BSZ   16
#define LSEQ  4096
#define CHUNKS 16
#define TLEN  (LSEQ / CHUNKS)   // 256
#define CN    (CH * NST)        // 16384

// ws layout (floats):
// [0,CN)     lam_r   [CN,2CN) lam_i   [2CN,3CN) e_hat
// [3CN,4CN)  lamT_r  [4CN,5CN) lamT_i
// [5CN, ...) states: [row(b*CH+c)][chunk m][n][{r,i}]  (B*CH*CHUNKS*NST*2 floats)

__global__ void setup_k(const float* __restrict__ A, const float* __restrict__ log_dt,
                        const float* __restrict__ E, float* __restrict__ ws) {
    int i = blockIdx.x * 256 + threadIdx.x;
    if (i >= CN) return;
    float a0 = A[2 * i], a1 = A[2 * i + 1];
    float sp = (a0 > 20.f) ? a0 : log1pf(expf(a0));   // softplus
    float dt = expf(log_dt[i]);
    float eh = E[i] * dt;
    float dar = -dt * sp;      // dtA_real  (<0)
    float dai = dt * a1;       // dtA_imag
    float mag = expf(dar);
    float s1, c1;
    sincosf(dai, &s1, &c1);
    ws[i]          = mag * c1;   // lam_r
    ws[CN + i]     = mag * s1;   // lam_i
    ws[2 * CN + i] = eh;
    float magT = expf(dar * (float)TLEN);
    float sT, cT;
    sincosf(dai * (float)TLEN, &sT, &cT);
    ws[3 * CN + i] = magT * cT;  // lamT_r
    ws[4 * CN + i] = magT * sT;  // lamT_i
}

__global__ __launch_bounds__(256) void phaseA_k(const float* __restrict__ x,
                                                const float* __restrict__ ws,
                                                float* __restrict__ states) {
    int tid = blockIdx.x * 256 + threadIdx.x;       // tid = row*CHUNKS + m
    int m   = tid & (CHUNKS - 1);
    int row = tid >> 4;
    int c   = row & (CH - 1);

    float lr[NST], li[NST], sr[NST], si[NST];
#pragma unroll
    for (int n = 0; n < NST; ++n) {
        lr[n] = ws[c * NST + n];
        li[n] = ws[CN + c * NST + n];
        sr[n] = 0.f;
        si[n] = 0.f;
    }
    const float4* xp = (const float4*)(x + (size_t)row * LSEQ + (size_t)m * TLEN);
#pragma unroll 2
    for (int j4 = 0; j4 < TLEN / 4; ++j4) {
        float4 xv = xp[j4];
        const float* xa = (const float*)&xv;
#pragma unroll
        for (int u = 0; u < 4; ++u) {
            float xu = xa[u];
#pragma unroll
            for (int n = 0; n < NST; ++n) {
                float srn = fmaf(lr[n], sr[n], fmaf(-li[n], si[n], xu));
                si[n] = fmaf(lr[n], si[n], li[n] * sr[n]);
                sr[n] = srn;
            }
        }
    }
    float* sp = states + (size_t)tid * (NST * 2);
#pragma unroll
    for (int n = 0; n < NST; ++n) {
        sp[2 * n]     = sr[n];
        sp[2 * n + 1] = si[n];
    }
}

__global__ void combine_k(const float* __restrict__ ws, float* __restrict__ states) {
    int tid = blockIdx.x * 256 + threadIdx.x;       // tid = row*NST + n
    if (tid >= BSZ * CH * NST) return;
    int n   = tid & (NST - 1);
    int row = tid >> 4;
    int c   = row & (CH - 1);
    float tr = ws[3 * CN + c * NST + n];
    float ti = ws[4 * CN + c * NST + n];
    float cr = 0.f, ci = 0.f;
    float* sp = states + (size_t)row * CHUNKS * NST * 2 + 2 * n;
    for (int m = 0; m < CHUNKS; ++m) {
        float slr = sp[(size_t)m * NST * 2];
        float sli = sp[(size_t)m * NST * 2 + 1];
        sp[(size_t)m * NST * 2]     = cr;   // overwrite with incoming state S_in[m]
        sp[(size_t)m * NST * 2 + 1] = ci;
        float ncr = fmaf(tr, cr, fmaf(-ti, ci, slr));
        float nci = fmaf(tr, ci, fmaf(ti, cr, sli));
        cr = ncr;
        ci = nci;
    }
}

__global__ __launch_bounds__(256) void phaseB_k(const float* __restrict__ x,
                                                const float* __restrict__ ws,
                                                const float* __restrict__ states,
                                                float* __restrict__ y) {
    int tid = blockIdx.x * 256 + threadIdx.x;       // tid = row*CHUNKS + m
    int m   = tid & (CHUNKS - 1);
    int row = tid >> 4;
    int c   = row & (CH - 1);

    float lr[NST], li[NST], eh[NST], sr[NST], si[NST];
    const float* sp = states + (size_t)tid * (NST * 2);
#pragma unroll
    for (int n = 0; n < NST; ++n) {
        lr[n] = ws[c * NST + n];
        li[n] = ws[CN + c * NST + n];
        eh[n] = ws[2 * CN + c * NST + n];
        sr[n] = sp[2 * n];
        si[n] = sp[2 * n + 1];
    }
    const float4* xp = (const float4*)(x + (size_t)row * LSEQ + (size_t)m * TLEN);
    float4*       yp = (float4*)(y + (size_t)row * LSEQ + (size_t)m * TLEN);
#pragma unroll 2
    for (int j4 = 0; j4 < TLEN / 4; ++j4) {
        float4 xv = xp[j4];
        float4 yv;
        const float* xa = (const float*)&xv;
        float*       ya = (float*)&yv;
#pragma unroll
        for (int u = 0; u < 4; ++u) {
            float xu = xa[u];
            float acc0 = 0.f, acc1 = 0.f;
#pragma unroll
            for (int n = 0; n < NST; ++n) {
                float srn = fmaf(lr[n], sr[n], fmaf(-li[n], si[n], xu));
                si[n] = fmaf(lr[n], si[n], li[n] * sr[n]);
                sr[n] = srn;
                if (n & 1) acc1 = fmaf(eh[n], srn, acc1);
                else       acc0 = fmaf(eh[n], srn, acc0);
            }
            ya[u] = acc0 + acc1;
        }
        yp[j4] = yv;
    }
}

extern "C" void kernel_launch(void* const* d_in, const int* in_sizes, int n_in,
                              void* d_out, int out_size, void* d_ws, size_t ws_size,
                              hipStream_t stream) {
    const float* x      = (const float*)d_in[0];
    const float* A      = (const float*)d_in[1];
    const float* log_dt = (const float*)d_in[4];
    const float* E      = (const float*)d_in[5];
    float* out = (float*)d_out;
    float* ws  = (float*)d_ws;
    float* states = ws + 5 * CN;

    setup_k<<<CN / 256, 256, 0, stream>>>(A, log_dt, E, ws);
    phaseA_k<<<(BSZ * CH * CHUNKS) / 256, 256, 0, stream>>>(x, ws, states);
    combine_k<<<(BSZ * CH * NST) / 256, 256, 0, stream>>>(ws, states);
    phaseB_k<<<(BSZ * CH * CHUNKS) / 256, 256, 0, stream>>>(x, ws, states, out);
}

// Round 2
// 320.654 us; speedup vs baseline: 1.2542x; 1.2542x over previous
//
#include <hip/hip_runtime.h>

#define CH     1024
#define NST    16
#define BSZ    16
#define LSEQ   4096
#define CHUNKS 16
#define TLEN   (LSEQ / CHUNKS)   // 256
#define CN     (CH * NST)        // 16384
#define TJ     32                // floats per thread per tile
#define NT     (TLEN / TJ)       // 8 tiles
#define LDSS   33                // padded stride (odd -> <=2-way bank aliasing)

// ws layout (floats):
// [0,CN) lam_r  [CN,2CN) lam_i  [2CN,3CN) e_hat  [3CN,4CN) lamT_r  [4CN,5CN) lamT_i
// [5CN,...) states: [row][chunk][n][{r,i}]

__global__ void setup_k(const float* __restrict__ A, const float* __restrict__ log_dt,
                        const float* __restrict__ E, float* __restrict__ ws) {
    int i = blockIdx.x * 256 + threadIdx.x;
    if (i >= CN) return;
    float a0 = A[2 * i], a1 = A[2 * i + 1];
    float sp = (a0 > 20.f) ? a0 : log1pf(expf(a0));
    float dt = expf(log_dt[i]);
    float eh = E[i] * dt;
    float dar = -dt * sp;
    float dai = dt * a1;
    float mag = expf(dar);
    float s1, c1;
    sincosf(dai, &s1, &c1);
    ws[i]          = mag * c1;
    ws[CN + i]     = mag * s1;
    ws[2 * CN + i] = eh;
    float magT = expf(dar * (float)TLEN);
    float sT, cT;
    sincosf(dai * (float)TLEN, &sT, &cT);
    ws[3 * CN + i] = magT * cT;
    ws[4 * CN + i] = magT * sT;
}

__global__ __launch_bounds__(256) void phaseA_k(const float* __restrict__ x,
                                                const float* __restrict__ ws,
                                                float* __restrict__ states) {
    __shared__ float lds[256 * LDSS];
    int t  = threadIdx.x;
    int r0 = blockIdx.x * 16;            // 16 rows per block
    int row = r0 + (t >> 4);
    int c   = row & (CH - 1);

    float lr[NST], li[NST], sr[NST], si[NST];
#pragma unroll
    for (int n = 0; n < NST; ++n) {
        lr[n] = ws[c * NST + n];
        li[n] = ws[CN + c * NST + n];
        sr[n] = 0.f;
        si[n] = 0.f;
    }

    for (int jt = 0; jt < NT; ++jt) {
#pragma unroll
        for (int i = 0; i < 8; ++i) {
            int g = t + 256 * i;
            int s = g >> 3, o = g & 7;
            int row_l = s >> 4, m = s & 15;
            float4 v = *(const float4*)(x + (size_t)(r0 + row_l) * LSEQ + m * TLEN + jt * TJ + o * 4);
            float* dst = &lds[s * LDSS + o * 4];
            dst[0] = v.x; dst[1] = v.y; dst[2] = v.z; dst[3] = v.w;
        }
        __syncthreads();
        const float* my = &lds[t * LDSS];
#pragma unroll
        for (int j = 0; j < TJ; ++j) {
            float xu = my[j];
#pragma unroll
            for (int n = 0; n < NST; ++n) {
                float srn = fmaf(lr[n], sr[n], fmaf(-li[n], si[n], xu));
                si[n] = fmaf(lr[n], si[n], li[n] * sr[n]);
                sr[n] = srn;
            }
        }
        __syncthreads();
    }
    float* sp = states + (size_t)(blockIdx.x * 256 + t) * (NST * 2);
#pragma unroll
    for (int n = 0; n < NST; ++n) {
        sp[2 * n]     = sr[n];
        sp[2 * n + 1] = si[n];
    }
}

__global__ void combine_k(const float* __restrict__ ws, float* __restrict__ states) {
    int tid = blockIdx.x * 256 + threadIdx.x;   // tid = row*NST + n
    if (tid >= BSZ * CH * NST) return;
    int n   = tid & (NST - 1);
    int row = tid >> 4;
    int c   = row & (CH - 1);
    float tr = ws[3 * CN + c * NST + n];
    float ti = ws[4 * CN + c * NST + n];
    float cr = 0.f, ci = 0.f;
    float* sp = states + (size_t)row * CHUNKS * NST * 2 + 2 * n;
    for (int m = 0; m < CHUNKS; ++m) {
        float slr = sp[(size_t)m * NST * 2];
        float sli = sp[(size_t)m * NST * 2 + 1];
        sp[(size_t)m * NST * 2]     = cr;
        sp[(size_t)m * NST * 2 + 1] = ci;
        float ncr = fmaf(tr, cr, fmaf(-ti, ci, slr));
        float nci = fmaf(tr, ci, fmaf(ti, cr, sli));
        cr = ncr;
        ci = nci;
    }
}

__global__ __launch_bounds__(256) void phaseB_k(const float* __restrict__ x,
                                                const float* __restrict__ ws,
                                                const float* __restrict__ states,
                                                float* __restrict__ y) {
    __shared__ float lds[256 * LDSS];
    int t  = threadIdx.x;
    int r0 = blockIdx.x * 16;
    int row = r0 + (t >> 4);
    int c   = row & (CH - 1);

    float lr[NST], li[NST], eh[NST], sr[NST], si[NST];
    const float* sp = states + (size_t)(blockIdx.x * 256 + t) * (NST * 2);
#pragma unroll
    for (int n = 0; n < NST; ++n) {
        lr[n] = ws[c * NST + n];
        li[n] = ws[CN + c * NST + n];
        eh[n] = ws[2 * CN + c * NST + n];
        sr[n] = sp[2 * n];
        si[n] = sp[2 * n + 1];
    }

    for (int jt = 0; jt < NT; ++jt) {
#pragma unroll
        for (int i = 0; i < 8; ++i) {
            int g = t + 256 * i;
            int s = g >> 3, o = g & 7;
            int row_l = s >> 4, m = s & 15;
            float4 v = *(const float4*)(x + (size_t)(r0 + row_l) * LSEQ + m * TLEN + jt * TJ + o * 4);
            float* dst = &lds[s * LDSS + o * 4];
            dst[0] = v.x; dst[1] = v.y; dst[2] = v.z; dst[3] = v.w;
        }
        __syncthreads();
        float* my = &lds[t * LDSS];
#pragma unroll
        for (int j = 0; j < TJ; ++j) {
            float xu = my[j];
            float acc0 = 0.f, acc1 = 0.f;
#pragma unroll
            for (int n = 0; n < NST; ++n) {
                float srn = fmaf(lr[n], sr[n], fmaf(-li[n], si[n], xu));
                si[n] = fmaf(lr[n], si[n], li[n] * sr[n]);
                sr[n] = srn;
                if (n & 1) acc1 = fmaf(eh[n], srn, acc1);
                else       acc0 = fmaf(eh[n], srn, acc0);
            }
            my[j] = acc0 + acc1;
        }
        __syncthreads();
#pragma unroll
        for (int i = 0; i < 8; ++i) {
            int g = t + 256 * i;
            int s = g >> 3, o = g & 7;
            int row_l = s >> 4, m = s & 15;
            const float* src = &lds[s * LDSS + o * 4];
            float4 v;
            v.x = src[0]; v.y = src[1]; v.z = src[2]; v.w = src[3];
            *(float4*)(y + (size_t)(r0 + row_l) * LSEQ + m * TLEN + jt * TJ + o * 4) = v;
        }
        __syncthreads();
    }
}

extern "C" void kernel_launch(void* const* d_in, const int* in_sizes, int n_in,
                              void* d_out, int out_size, void* d_ws, size_t ws_size,
                              hipStream_t stream) {
    const float* x      = (const float*)d_in[0];
    const float* A      = (const float*)d_in[1];
    const float* log_dt = (const float*)d_in[4];
    const float* E      = (const float*)d_in[5];
    float* out = (float*)d_out;
    float* ws  = (float*)d_ws;
    float* states = ws + 5 * CN;

    setup_k<<<CN / 256, 256, 0, stream>>>(A, log_dt, E, ws);
    phaseA_k<<<(BSZ * CH * CHUNKS) / 256, 256, 0, stream>>>(x, ws, states);
    combine_k<<<(BSZ * CH * NST) / 256, 256, 0, stream>>>(ws, states);
    phaseB_k<<<(BSZ * CH * CHUNKS) / 256, 256, 0, stream>>>(x, ws, states, out);
}

// Round 3
// 240.052 us; speedup vs baseline: 1.6753x; 1.3358x over previous
//
#include <hip/hip_runtime.h>

#define CH    1024
#define NST   16
#define BSZ   16
#define LSEQ  4096
#define T     64                 // chunk length; lane m scans chunk m
#define CN    (CH * NST)         // 16384
#define LP    65                 // padded LDS column stride

// ws layout (floats): [0,CN) lam_r  [CN,2CN) lam_i  [2CN,3CN) e_hat
//                     [3CN,4CN) q_r (=lam^64 real)  [4CN,5CN) q_i

__global__ void setup_k(const float* __restrict__ A, const float* __restrict__ log_dt,
                        const float* __restrict__ E, float* __restrict__ ws) {
    int i = blockIdx.x * 256 + threadIdx.x;
    if (i >= CN) return;
    float a0 = A[2 * i], a1 = A[2 * i + 1];
    float sp = (a0 > 20.f) ? a0 : log1pf(expf(a0));   // softplus
    float dt = expf(log_dt[i]);
    float eh = E[i] * dt;
    float dar = -dt * sp;
    float dai = dt * a1;
    float mag = expf(dar);
    float s1, c1;
    sincosf(dai, &s1, &c1);
    ws[i]          = mag * c1;   // lam_r
    ws[CN + i]     = mag * s1;   // lam_i
    ws[2 * CN + i] = eh;
    float magT = expf(dar * (float)T);
    float sT, cT;
    sincosf(dai * (float)T, &sT, &cT);
    ws[3 * CN + i] = magT * cT;  // q_r
    ws[4 * CN + i] = magT * sT;  // q_i
}

__global__ __launch_bounds__(64) void scan_k(const float* __restrict__ x,
                                             const float* __restrict__ ws,
                                             float* __restrict__ y) {
    __shared__ float lds[64 * LP];           // lds[j*LP + m] = x[m*64 + j]
    const int lane = threadIdx.x;            // 0..63 = chunk index m
    const int row  = blockIdx.x;             // b*CH + c
    const int c    = row & (CH - 1);
    const float* xr = x + (size_t)row * LSEQ;
    float*       yr = y + (size_t)row * LSEQ;

    // ---- stage x -> LDS (transposed), fully coalesced global reads ----
    {
        const int j0 = 4 * (lane & 15);
#pragma unroll
        for (int r = 0; r < 16; ++r) {
            float4 v = *(const float4*)(xr + 256 * r + 4 * lane);
            int m = 4 * r + (lane >> 4);
            lds[(j0 + 0) * LP + m] = v.x;
            lds[(j0 + 1) * LP + m] = v.y;
            lds[(j0 + 2) * LP + m] = v.z;
            lds[(j0 + 3) * LP + m] = v.w;
        }
    }

    // ---- params ----
    float lr[NST], li[NST];
#pragma unroll
    for (int n = 0; n < NST; ++n) {
        lr[n] = ws[c * NST + n];
        li[n] = ws[CN + c * NST + n];
    }

    // ---- pass 1: local chunk scan from zero ----
    float sr[NST], si[NST];
#pragma unroll
    for (int n = 0; n < NST; ++n) { sr[n] = 0.f; si[n] = 0.f; }
#pragma unroll 4
    for (int j = 0; j < T; ++j) {
        float xu = lds[j * LP + lane];
#pragma unroll
        for (int n = 0; n < NST; ++n) {
            float srn = fmaf(lr[n], sr[n], fmaf(-li[n], si[n], xu));
            si[n] = fmaf(lr[n], si[n], li[n] * sr[n]);
            sr[n] = srn;
        }
    }

    // ---- wave-level combine: inclusive scan A[m] = sum_{m'<=m} q^(m-m') S_end[m'] ----
    {
        float pqr[NST], pqi[NST];
#pragma unroll
        for (int n = 0; n < NST; ++n) {
            pqr[n] = ws[3 * CN + c * NST + n];
            pqi[n] = ws[4 * CN + c * NST + n];
        }
#pragma unroll
        for (int d = 1; d < 64; d <<= 1) {
#pragma unroll
            for (int n = 0; n < NST; ++n) {
                float ur = __shfl_up(sr[n], d);
                float ui = __shfl_up(si[n], d);
                ur = (lane >= d) ? ur : 0.f;
                ui = (lane >= d) ? ui : 0.f;
                sr[n] = fmaf(pqr[n], ur, fmaf(-pqi[n], ui, sr[n]));
                si[n] = fmaf(pqr[n], ui, fmaf(pqi[n], ur, si[n]));
            }
#pragma unroll
            for (int n = 0; n < NST; ++n) {       // q <- q^2
                float t = fmaf(pqr[n], pqr[n], -(pqi[n] * pqi[n]));
                pqi[n] = 2.f * pqr[n] * pqi[n];
                pqr[n] = t;
            }
        }
        // S_in[m] = A[m-1], zero for m=0
#pragma unroll
        for (int n = 0; n < NST; ++n) {
            float ar = __shfl_up(sr[n], 1);
            float ai = __shfl_up(si[n], 1);
            sr[n] = (lane > 0) ? ar : 0.f;
            si[n] = (lane > 0) ? ai : 0.f;
        }
    }

    // ---- pass 2: re-scan with incoming state, emit y into LDS in place ----
    float eh[NST];
#pragma unroll
    for (int n = 0; n < NST; ++n) eh[n] = ws[2 * CN + c * NST + n];
#pragma unroll 4
    for (int j = 0; j < T; ++j) {
        float xu = lds[j * LP + lane];
        float a0 = 0.f, a1 = 0.f;
#pragma unroll
        for (int n = 0; n < NST; ++n) {
            float srn = fmaf(lr[n], sr[n], fmaf(-li[n], si[n], xu));
            si[n] = fmaf(lr[n], si[n], li[n] * sr[n]);
            sr[n] = srn;
            if (n & 1) a1 = fmaf(eh[n], srn, a1);
            else       a0 = fmaf(eh[n], srn, a0);
        }
        lds[j * LP + lane] = a0 + a1;
    }

    // ---- store y out (transposed back), fully coalesced ----
    {
        const int j0 = 4 * (lane & 15);
#pragma unroll
        for (int r = 0; r < 16; ++r) {
            int m = 4 * r + (lane >> 4);
            float4 v;
            v.x = lds[(j0 + 0) * LP + m];
            v.y = lds[(j0 + 1) * LP + m];
            v.z = lds[(j0 + 2) * LP + m];
            v.w = lds[(j0 + 3) * LP + m];
            *(float4*)(yr + 256 * r + 4 * lane) = v;
        }
    }
}

extern "C" void kernel_launch(void* const* d_in, const int* in_sizes, int n_in,
                              void* d_out, int out_size, void* d_ws, size_t ws_size,
                              hipStream_t stream) {
    const float* x      = (const float*)d_in[0];
    const float* A      = (const float*)d_in[1];
    const float* log_dt = (const float*)d_in[4];
    const float* E      = (const float*)d_in[5];
    float* out = (float*)d_out;
    float* ws  = (float*)d_ws;

    setup_k<<<CN / 256, 256, 0, stream>>>(A, log_dt, E, ws);
    scan_k<<<BSZ * CH, 64, 0, stream>>>(x, ws, out);
}